// Round 9
// baseline (333.819 us; speedup 1.0000x reference)
//
#include <hip/hip_runtime.h>
#include <hip/hip_bf16.h>
#include <math.h>

#define D_MODEL 1024
#define D_HIDDEN 4096
#define N_EXP 8
#define N_TOK 4096
#define MBS 40   // max 128-row m-slots (worst case 39)

typedef __attribute__((ext_vector_type(8))) __bf16 bf16x8_t;
typedef __attribute__((ext_vector_type(4))) float f32x4_t;

// ---- workspace layout (bytes) ----
// counts @0, prefix @128 (9 ints), bucket @256 (128KB)
// xb  @256K        : 8 MB   (fallback only)
// HT  @256K+8M     : 40 MB  (tiled h chunks [mbg][kc64][128m][slot^8][16B])
// W1T @256K+50M    : 64 MB  ([e][nb128][kc16][128n][slot^8][16B]) -> reused as FFN2 partials (42MB)
// W2T @256K+114M   : 64 MB  ([e][nb128][kc64][128n][slot^8][16B])
// AE  @256K+178M   : 10 MB  ([mbg][kc16][128m][slot^8][16B])
#define WS_PREFIX_OFF 128
#define WS_BUCKET_OFF 256
#define WS_XB_OFF     ((size_t)1 << 18)
#define WS_HT_OFF     (((size_t)1 << 18) + ((size_t)8 << 20))
#define WS_W1T_OFF    (((size_t)1 << 18) + ((size_t)50 << 20))
#define WS_W2T_OFF    (((size_t)1 << 18) + ((size_t)114 << 20))
#define WS_AE_OFF     (((size_t)1 << 18) + ((size_t)178 << 20))
#define WS_NEED       (((size_t)1 << 18) + ((size_t)189 << 20))

__device__ __forceinline__ void gload16(const void* g, void* l) {
    __builtin_amdgcn_global_load_lds(
        (__attribute__((address_space(1))) void*)(g),
        (__attribute__((address_space(3))) void*)(l),
        16, 0, 0);
}

__global__ __launch_bounds__(64) void init_counts(int* counts) {
    if (threadIdx.x < N_EXP) counts[threadIdx.x] = 0;
}

__global__ __launch_bounds__(64) void prefix_kernel(const int* counts, int* prefix) {
    if (threadIdx.x == 0) {
        int s = 0;
        prefix[0] = 0;
#pragma unroll
        for (int e = 0; e < N_EXP; ++e) { s += (counts[e] + 127) >> 7; prefix[e + 1] = s; }
    }
}

// Router: one wave per token, fp64 logit accumulation; also emits xb (fallback).
__global__ __launch_bounds__(256) void router_kernel(
    const float* __restrict__ x, const float* __restrict__ Wg,
    const float* __restrict__ bg, int* __restrict__ counts,
    int* __restrict__ bucket, __hip_bfloat16* __restrict__ xb)
{
    const int wid  = threadIdx.x >> 6;
    const int lane = threadIdx.x & 63;
    const int t    = blockIdx.x * 4 + wid;
    const float* xr = x + (size_t)t * D_MODEL;

    double acc[N_EXP];
#pragma unroll
    for (int e = 0; e < N_EXP; ++e) acc[e] = 0.0;

#pragma unroll
    for (int j = 0; j < D_MODEL / 64; ++j) {
        const int d = j * 64 + lane;
        const float xv = xr[d];
        xb[(size_t)t * D_MODEL + d] = __float2bfloat16(xv);
        const float4* wr = (const float4*)(Wg + (size_t)d * N_EXP);
        const float4 w0 = wr[0], w1 = wr[1];
        const double xd = (double)xv;
        acc[0] += xd * (double)w0.x; acc[1] += xd * (double)w0.y;
        acc[2] += xd * (double)w0.z; acc[3] += xd * (double)w0.w;
        acc[4] += xd * (double)w1.x; acc[5] += xd * (double)w1.y;
        acc[6] += xd * (double)w1.z; acc[7] += xd * (double)w1.w;
    }
#pragma unroll
    for (int e = 0; e < N_EXP; ++e) {
        double v = acc[e];
#pragma unroll
        for (int off = 32; off >= 1; off >>= 1) v += __shfl_xor(v, off, 64);
        acc[e] = v + (double)bg[e];
    }
    if (lane == 0) {
        int best = 0; double bv = acc[0];
#pragma unroll
        for (int e = 1; e < N_EXP; ++e)
            if (acc[e] > bv) { bv = acc[e]; best = e; }
        const int pos = atomicAdd(&counts[best], 1);
        bucket[best * N_TOK + pos] = t;
    }
}

// W fp32 [e][k][NT] -> tiled chunks [e][nb128][kc][128n][slot^][16B] (16KB each)
// Input phase vectorized: 8 float4 reads + 8 ds_write_b64 per thread.
template<int KT, int NT>
__global__ __launch_bounds__(256) void convert_w(
    const float* __restrict__ W, __hip_bfloat16* __restrict__ Wt)
{
    constexpr int NB = NT / 128, KC = KT / 64;
    const int nblk = blockIdx.x, kc = blockIdx.y, e = blockIdx.z;
    const int k0 = kc * 64, n0 = nblk * 128;
    const int tid = threadIdx.x;
    __shared__ __hip_bfloat16 Lt[128 * 68];   // [n][k], row stride 136B

    const int nq  = tid & 31;                 // n-quad (4 cols)
    const int kq2 = tid >> 5;                 // covers k-quads kq2, kq2+8
#pragma unroll
    for (int h = 0; h < 2; ++h) {
        const int kq = kq2 + h * 8;
        const float* src = W + (size_t)e * KT * NT + (size_t)(k0 + kq * 4) * NT + n0 + nq * 4;
        const float4 v0 = *(const float4*)(src);
        const float4 v1 = *(const float4*)(src + (size_t)NT);
        const float4 v2 = *(const float4*)(src + (size_t)2 * NT);
        const float4 v3 = *(const float4*)(src + (size_t)3 * NT);
#pragma unroll
        for (int i = 0; i < 4; ++i) {
            const int n = nq * 4 + i;
            union { __hip_bfloat16 hh[4]; unsigned long long u; } pk;
            pk.hh[0] = __float2bfloat16(((const float*)&v0)[i]);
            pk.hh[1] = __float2bfloat16(((const float*)&v1)[i]);
            pk.hh[2] = __float2bfloat16(((const float*)&v2)[i]);
            pk.hh[3] = __float2bfloat16(((const float*)&v3)[i]);
            *(unsigned long long*)((char*)Lt + (size_t)n * 136 + kq * 8) = pk.u;
        }
    }
    __syncthreads();

    char* outc = (char*)Wt + (((size_t)e * NB + nblk) * KC + kc) * 16384;
    const int n = tid >> 1, half = tid & 1;
#pragma unroll
    for (int s = 0; s < 4; ++s) {
        const int slot = half * 4 + s;
        const int ko = slot ^ (n & 7);
        const uint4 v = *(const uint4*)((const char*)Lt + (size_t)n * 136 + ko * 16);
        *(uint4*)(outc + (size_t)n * 128 + slot * 16) = v;
    }
}

// gather x rows by bucket into tiled A chunks [mbg][kc][128m][slot^][16B]
__global__ __launch_bounds__(256) void gather_a(
    const float* __restrict__ x, const int* __restrict__ counts,
    const int* __restrict__ prefix, const int* __restrict__ bucket,
    __hip_bfloat16* __restrict__ Ae)
{
    const int mbg = blockIdx.x, kc = blockIdx.y;
    if (mbg >= prefix[8]) return;
    int e = 0;
#pragma unroll
    for (int q = 1; q < 8; ++q) if (mbg >= prefix[q]) e = q;
    const int cnt  = counts[e];
    const int mblk = mbg - prefix[e];
    const int tid  = threadIdx.x;
    const int m = tid >> 1, half = tid & 1;
    int idx = mblk * 128 + m;
    if (idx >= cnt) idx = cnt - 1;
    const int tok = bucket[e * N_TOK + idx];
    const float* src = x + (size_t)tok * D_MODEL + kc * 64 + half * 32;
    char* dst = (char*)Ae + ((size_t)mbg * 16 + kc) * 16384 + (size_t)m * 128;
#pragma unroll
    for (int s = 0; s < 4; ++s) {
        const float4 a = *(const float4*)(src + s * 8);
        const float4 b = *(const float4*)(src + s * 8 + 4);
        union { __hip_bfloat16 hh[8]; uint4 u; } pk;
#pragma unroll
        for (int j = 0; j < 4; ++j) {
            pk.hh[j]     = __float2bfloat16(((const float*)&a)[j]);
            pk.hh[j + 4] = __float2bfloat16(((const float*)&b)[j]);
        }
        const int ko = half * 4 + s;
        *(uint4*)(dst + ((ko ^ (m & 7)) << 4)) = pk.u;
    }
}

// ===== wide grouped GEMM: 128 x 256 x 64, optional split-K, m97 staging ======
// 4 waves, wave tile 64x128 (acc[4][8]): 64 MFMA : 24 ds_read per wave-step.
// Staged bytes/FLOP = 48KB / 4.2MF (2/3 of the 128^2 tile) — attacks the
// ~28 GB/s/CU global_load_lds service wall identified in R8.
template<int K_TOT, int N_TOT, int SPLITS, bool IS_FFN1>
__global__ __launch_bounds__(256, 2) void ffn_gemm_w(
    const __hip_bfloat16* __restrict__ At,
    const __hip_bfloat16* __restrict__ Wt,
    const float* __restrict__ bias,
    const int* __restrict__ counts,
    const int* __restrict__ prefix,
    __hip_bfloat16* __restrict__ hout,   // FFN1: tiled h chunks
    float* __restrict__ pout)            // FFN2: fp32 partials [split][mbg][128][1024]
{
    constexpr int KC     = K_TOT / 64;
    constexpr int KSTEPS = KC / SPLITS;
    constexpr int NBW    = N_TOT / 256;
    constexpr int NB128  = N_TOT / 128;
    constexpr int NWG    = NBW * SPLITS * MBS;

    const int orig = blockIdx.x;
    const int wg   = (orig & 7) * (NWG >> 3) + (orig >> 3);
    const int nblk = wg / (SPLITS * MBS);
    const int r2   = wg % (SPLITS * MBS);
    const int split = r2 / MBS;
    const int mbg   = r2 % MBS;
    if (mbg >= prefix[8]) return;
    int e = 0;
#pragma unroll
    for (int q = 1; q < 8; ++q) if (mbg >= prefix[q]) e = q;
    const int n0 = nblk * 256;

    const int tid  = threadIdx.x;
    const int lane = tid & 63;
    const int wid  = tid >> 6;
    const int wm   = wid >> 1, wn = wid & 1;

    __shared__ char As[16384];
    __shared__ char Bs[32768];

    const char* Ab  = (const char*)At + ((size_t)mbg * KC + split * KSTEPS) * 16384;
    const char* Bb0 = (const char*)Wt + (((size_t)e * NB128 + nblk * 2) * KC + split * KSTEPS) * 16384;
    const char* Bb1 = Bb0 + (size_t)KC * 16384;
    const int off = wid * 4096 + lane * 16;
    char* lA  = As + wid * 4096;
    char* lB0 = Bs + wid * 4096;
    char* lB1 = Bs + 16384 + wid * 4096;

    f32x4_t acc[4][8];
#pragma unroll
    for (int f = 0; f < 4; ++f)
#pragma unroll
        for (int g = 0; g < 8; ++g) acc[f][g] = (f32x4_t){0.f, 0.f, 0.f, 0.f};

    for (int t = 0; t < KSTEPS; ++t) {
        const char* Ac = Ab  + (size_t)t * 16384 + off;
        const char* B0 = Bb0 + (size_t)t * 16384 + off;
        const char* B1 = Bb1 + (size_t)t * 16384 + off;
#pragma unroll
        for (int i = 0; i < 4; ++i) gload16(Ac + i * 1024, lA + i * 1024);
#pragma unroll
        for (int i = 0; i < 4; ++i) gload16(B0 + i * 1024, lB0 + i * 1024);
#pragma unroll
        for (int i = 0; i < 4; ++i) gload16(B1 + i * 1024, lB1 + i * 1024);
        __syncthreads();   // vmcnt drain: tile ready

#pragma unroll
        for (int kk = 0; kk < 2; ++kk) {
            uint4 af[4], bf[8];
            const int ko = kk * 4 + (lane >> 4);
#pragma unroll
            for (int f = 0; f < 4; ++f) {
                const int r = wm * 64 + f * 16 + (lane & 15);
                af[f] = *(const uint4*)(As + r * 128 + ((ko ^ (r & 7)) << 4));
            }
#pragma unroll
            for (int g = 0; g < 8; ++g) {
                const int n = wn * 128 + g * 16 + (lane & 15);
                bf[g] = *(const uint4*)(Bs + n * 128 + ((ko ^ (n & 7)) << 4));
            }
#pragma unroll
            for (int f = 0; f < 4; ++f)
#pragma unroll
                for (int g = 0; g < 8; ++g)
                    acc[f][g] = __builtin_amdgcn_mfma_f32_16x16x32_bf16(
                        __builtin_bit_cast(bf16x8_t, af[f]),
                        __builtin_bit_cast(bf16x8_t, bf[g]),
                        acc[f][g], 0, 0, 0);
        }
        __syncthreads();
    }

    // ---- epilogue: C/D layout col=lane&15, row=(lane>>4)*4+j ----
    if (IS_FFN1) {
        char* hb = (char*)hout + (size_t)mbg * (D_HIDDEN / 64) * 16384;
#pragma unroll
        for (int f = 0; f < 4; ++f) {
#pragma unroll
            for (int j = 0; j < 4; ++j) {
                const int m = wm * 64 + f * 16 + (lane >> 4) * 4 + j;
#pragma unroll
                for (int g = 0; g < 8; ++g) {
                    const int col = n0 + wn * 128 + g * 16 + (lane & 15);
                    float v = acc[f][g][j] + bias[e * N_TOT + col];
                    v = 0.5f * v * (1.0f + erff(v * 0.70710678118654752f));
                    const int kc = col >> 6, kw = col & 63, ko = kw >> 3, b = kw & 7;
                    *(__hip_bfloat16*)(hb + ((size_t)kc * 128 + m) * 128 +
                                       (((ko ^ (m & 7)) << 4) + (b << 1))) = __float2bfloat16(v);
                }
            }
        }
    } else {
        float* pb = pout + ((size_t)(split * MBS + mbg) * 128) * 1024;
#pragma unroll
        for (int f = 0; f < 4; ++f) {
#pragma unroll
            for (int j = 0; j < 4; ++j) {
                const int m = wm * 64 + f * 16 + (lane >> 4) * 4 + j;
#pragma unroll
                for (int g = 0; g < 8; ++g) {
                    const int col = n0 + wn * 128 + g * 16 + (lane & 15);
                    pb[(size_t)m * 1024 + col] = acc[f][g][j];
                }
            }
        }
    }
}

// reduce FFN2 partials: out[tok] = p0 + p1 + bias (deterministic two-pass)
__global__ __launch_bounds__(256) void reduce_out(
    const float* __restrict__ P, const float* __restrict__ b2,
    const int* __restrict__ counts, const int* __restrict__ prefix,
    const int* __restrict__ bucket, float* __restrict__ out)
{
    const int slot = blockIdx.x;
    if (slot >= prefix[8]) return;
    int e = 0;
#pragma unroll
    for (int q = 1; q < 8; ++q) if (slot >= prefix[q]) e = q;
    const int cnt  = counts[e];
    const int mblk = slot - prefix[e];
    const int r    = blockIdx.y * 4 + (threadIdx.x >> 6);
    const int idx  = mblk * 128 + r;
    if (idx >= cnt) return;
    const int tok  = bucket[e * N_TOK + idx];
    const int lane = threadIdx.x & 63;
    const float* p0 = P + ((size_t)slot * 128 + r) * 1024;
    const float* p1 = P + ((size_t)(MBS + slot) * 128 + r) * 1024;
    const float* bb = b2 + e * 1024;
    float* op = out + (size_t)tok * 1024;
#pragma unroll
    for (int j = 0; j < 4; ++j) {
        const int c = j * 256 + lane * 4;
        const float4 a = *(const float4*)(p0 + c);
        const float4 b = *(const float4*)(p1 + c);
        const float4 w = *(const float4*)(bb + c);
        float4 v;
        v.x = a.x + b.x + w.x; v.y = a.y + b.y + w.y;
        v.z = a.z + b.z + w.z; v.w = a.w + b.w + w.w;
        *(float4*)(op + c) = v;
    }
}

// ===================== fp32-W fallback (used if ws too small) =================
template<int K_TOT, int N_TOT, bool IS_FFN1>
__global__ __launch_bounds__(256, 2) void ffn_gemm_f32(
    const __hip_bfloat16* __restrict__ A,
    const float* __restrict__ W,
    const float* __restrict__ bias,
    const int* __restrict__ counts,
    const int* __restrict__ bucket,
    __hip_bfloat16* __restrict__ hout,
    float* __restrict__ yout)
{
    const int e   = blockIdx.z;
    const int cnt = counts[e];
    const int m0  = blockIdx.y * 128;
    if (m0 >= cnt) return;
    const int n0   = blockIdx.x * 128;
    const int tid  = threadIdx.x;
    const int lane = tid & 63;
    const int wid  = tid >> 6;
    const int wm   = wid >> 1, wn = wid & 1;

    __shared__ __hip_bfloat16 As[128 * 64];
    __shared__ __hip_bfloat16 Bs[128 * 64];
    __shared__ int s_tok[128];

    if (tid < 128) {
        int idx = m0 + tid;
        if (idx >= cnt) idx = cnt - 1;
        s_tok[tid] = bucket[e * N_TOK + idx];
    }
    __syncthreads();

    const __hip_bfloat16* gA[4]; char* lA[4];
#pragma unroll
    for (int i = 0; i < 4; ++i) {
        const int r = wid * 32 + i * 8 + (lane >> 3);
        gA[i] = A + (size_t)s_tok[r] * K_TOT + (((lane & 7) ^ (r & 7)) << 3);
        lA[i] = (char*)As + (size_t)(wid * 32 + i * 8) * 128;
    }
    const int ko_t = lane & 7;
    const int nq   = wid * 8 + (lane >> 3);
    const float* wb = W + (size_t)e * K_TOT * N_TOT + (size_t)(ko_t * 8) * N_TOT + n0 + nq * 4;

    f32x4_t acc[4][4];
#pragma unroll
    for (int f = 0; f < 4; ++f)
#pragma unroll
        for (int g = 0; g < 4; ++g) acc[f][g] = (f32x4_t){0.f, 0.f, 0.f, 0.f};

    for (int k0 = 0; k0 < K_TOT; k0 += 64) {
#pragma unroll
        for (int i = 0; i < 4; ++i) gload16(gA[i] + k0, lA[i]);
        const float* wk = wb + (size_t)k0 * N_TOT;
        float4 v[8];
#pragma unroll
        for (int j = 0; j < 8; ++j) v[j] = *(const float4*)(wk + (size_t)j * N_TOT);
#pragma unroll
        for (int i = 0; i < 4; ++i) {
            const int n = nq * 4 + i;
            union { __hip_bfloat16 hh[8]; uint4 u; } pk;
#pragma unroll
            for (int j = 0; j < 8; ++j) pk.hh[j] = __float2bfloat16(((const float*)&v[j])[i]);
            *(uint4*)((char*)Bs + n * 128 + ((ko_t ^ (n & 7)) << 4)) = pk.u;
        }
        __syncthreads();

#pragma unroll
        for (int kk = 0; kk < 2; ++kk) {
            uint4 af[4], bf[4];
            const int ko = kk * 4 + (lane >> 4);
#pragma unroll
            for (int f = 0; f < 4; ++f) {
                const int r = wm * 64 + f * 16 + (lane & 15);
                af[f] = *(const uint4*)((const char*)As + r * 128 + ((ko ^ (r & 7)) << 4));
            }
#pragma unroll
            for (int g = 0; g < 4; ++g) {
                const int n = wn * 64 + g * 16 + (lane & 15);
                bf[g] = *(const uint4*)((const char*)Bs + n * 128 + ((ko ^ (n & 7)) << 4));
            }
#pragma unroll
            for (int f = 0; f < 4; ++f)
#pragma unroll
                for (int g = 0; g < 4; ++g)
                    acc[f][g] = __builtin_amdgcn_mfma_f32_16x16x32_bf16(
                        __builtin_bit_cast(bf16x8_t, af[f]),
                        __builtin_bit_cast(bf16x8_t, bf[g]),
                        acc[f][g], 0, 0, 0);
        }
        __syncthreads();
    }

#pragma unroll
    for (int f = 0; f < 4; ++f) {
#pragma unroll
        for (int j = 0; j < 4; ++j) {
            const int rl = wm * 64 + f * 16 + (lane >> 4) * 4 + j;
            const bool ok = (m0 + rl) < cnt;
            const int tok = s_tok[rl];
#pragma unroll
            for (int g = 0; g < 4; ++g) {
                const int col = n0 + wn * 64 + g * 16 + (lane & 15);
                float v = acc[f][g][j] + bias[e * N_TOT + col];
                if (IS_FFN1) {
                    v = 0.5f * v * (1.0f + erff(v * 0.70710678118654752f));
                    if (ok) hout[(size_t)tok * N_TOT + col] = __float2bfloat16(v);
                } else {
                    if (ok) yout[(size_t)tok * N_TOT + col] = v;
                }
            }
        }
    }
}

extern "C" void kernel_launch(void* const* d_in, const int* in_sizes, int n_in,
                              void* d_out, int out_size, void* d_ws, size_t ws_size,
                              hipStream_t stream) {
    const float* x  = (const float*)d_in[0];
    const float* Wg = (const float*)d_in[1];
    const float* bg = (const float*)d_in[2];
    const float* W1 = (const float*)d_in[3];
    const float* b1 = (const float*)d_in[4];
    const float* W2 = (const float*)d_in[5];
    const float* b2 = (const float*)d_in[6];
    float* out = (float*)d_out;

    char* ws = (char*)d_ws;
    int* counts = (int*)(ws);
    int* prefix = (int*)(ws + WS_PREFIX_OFF);
    int* bucket = (int*)(ws + WS_BUCKET_OFF);
    __hip_bfloat16* xb  = (__hip_bfloat16*)(ws + WS_XB_OFF);
    __hip_bfloat16* ht  = (__hip_bfloat16*)(ws + WS_HT_OFF);
    __hip_bfloat16* w1t = (__hip_bfloat16*)(ws + WS_W1T_OFF);
    __hip_bfloat16* w2t = (__hip_bfloat16*)(ws + WS_W2T_OFF);
    __hip_bfloat16* ae  = (__hip_bfloat16*)(ws + WS_AE_OFF);
    float* partials     = (float*)(ws + WS_W1T_OFF);   // reuse W1T after FFN1

    init_counts<<<dim3(1), dim3(64), 0, stream>>>(counts);
    router_kernel<<<dim3(N_TOK / 4), dim3(256), 0, stream>>>(x, Wg, bg, counts, bucket, xb);
    prefix_kernel<<<dim3(1), dim3(64), 0, stream>>>(counts, prefix);

    if (ws_size >= WS_NEED) {
        convert_w<D_MODEL, D_HIDDEN><<<dim3(32, 16, N_EXP), dim3(256), 0, stream>>>(W1, w1t);
        convert_w<D_HIDDEN, D_MODEL><<<dim3(8, 64, N_EXP), dim3(256), 0, stream>>>(W2, w2t);
        gather_a<<<dim3(MBS, 16), dim3(256), 0, stream>>>(x, counts, prefix, bucket, ae);
        // FFN1: K=1024, N=4096, BN=256 -> grid 40*16 = 640
        ffn_gemm_w<D_MODEL, D_HIDDEN, 1, true>
            <<<dim3(MBS * (D_HIDDEN / 256)), dim3(256), 0, stream>>>(
                ae, w1t, b1, counts, prefix, ht, nullptr);
        // FFN2: K=4096, N=1024, BN=256, split-K=2 -> grid 40*4*2 = 320
        ffn_gemm_w<D_HIDDEN, D_MODEL, 2, false>
            <<<dim3(MBS * (D_MODEL / 256) * 2), dim3(256), 0, stream>>>(
                ht, w2t, nullptr, counts, prefix, nullptr, partials);
        reduce_out<<<dim3(MBS, 32), dim3(256), 0, stream>>>(
            partials, b2, counts, prefix, bucket, out);
    } else {
        __hip_bfloat16* h = ht;   // row-major in fallback
        ffn_gemm_f32<D_MODEL, D_HIDDEN, true>
            <<<dim3(D_HIDDEN / 128, N_TOK / 128, N_EXP), dim3(256), 0, stream>>>(
                xb, W1, b1, counts, bucket, h, nullptr);
        ffn_gemm_f32<D_HIDDEN, D_MODEL, false>
            <<<dim3(D_MODEL / 128, N_TOK / 128, N_EXP), dim3(256), 0, stream>>>(
                h, W2, b2, counts, bucket, nullptr, out);
    }
}